// Round 8
// baseline (691.536 us; speedup 1.0000x reference)
//
#include <hip/hip_runtime.h>
#include <hip/hip_bf16.h>
#include <hip/hip_cooperative_groups.h>
#include <cstdint>
#include <cstddef>

namespace cg = cooperative_groups;

#define N_NODES 50000
#define N_EDGES 800000
#define FIN 512
#define HW_ 128
#define NCLS 16
#define SCAN_NB 196  // ceil(50000/256)

typedef __attribute__((ext_vector_type(4))) float floatx4;
typedef __attribute__((ext_vector_type(4))) int int4v;
typedef __bf16 bf16x8 __attribute__((ext_vector_type(8)));

__device__ __forceinline__ void glds16(const __bf16* g, __bf16* l) {
  __builtin_amdgcn_global_load_lds(
      (const __attribute__((address_space(1))) void*)g,
      (__attribute__((address_space(3))) void*)l, 16, 0, 0);
}

// ------- prep: w1 transpose | U=w2@wf | constc -------
// Ut[80][384] bf16: Ut[16p+c][128j+r] = U_{(p-j) j}[r][c] (0 if p-j not in 0..2)
#define PREP_NT1 48            // 3 * (512/64) * (128/64)
#define PREP_NU 120            // 80*384 / 256
__global__ __launch_bounds__(256) void k_prep(
    const float* __restrict__ w1, __bf16* __restrict__ w1t,
    const float* __restrict__ w2, const float* __restrict__ wf,
    __bf16* __restrict__ Ut,
    const float* __restrict__ b2, const float* __restrict__ bfv,
    float* __restrict__ cc) {
  int b = blockIdx.x;
  int tid = threadIdx.x;
  if (b < PREP_NT1) {
    // 64x64 tile transpose: w1[K][128] -> w1t[128][K], fp32 -> bf16
    int tb = b;
    const int K = FIN;
    int tilesK = K >> 6;
    int i = tb / (tilesK * 2);
    int rr = tb - i * tilesK * 2;
    int kt = rr >> 1;
    int nt = rr & 1;
    const float* wS = w1 + (size_t)i * K * 128;
    __bf16* wtS = w1t + (size_t)i * 128 * K;
    int k0 = kt * 64, n0 = nt * 64;
    __shared__ float tile[64][65];
    int tc = tid & 63, tr = tid >> 6;
#pragma unroll
    for (int q = 0; q < 16; q++) {
      int row = tr + q * 4;
      tile[row][tc] = wS[(size_t)(k0 + row) * 128 + n0 + tc];
    }
    __syncthreads();
#pragma unroll
    for (int q = 0; q < 16; q++) {
      int nr = tr + q * 4;
      wtS[(size_t)(n0 + nr) * K + k0 + tc] = (__bf16)tile[tc][nr];
    }
  } else if (b < PREP_NT1 + PREP_NU) {
    int t = (b - PREP_NT1) * 256 + tid;  // [0, 30720)
    int col = t / 384;            // 0..79 = 16p + c
    int q = t - col * 384;        // 0..383 = 128j + r
    int p = col >> 4, c = col & 15;
    int j = q >> 7;
    int i = p - j;
    float val = 0.f;
    if (i >= 0 && i <= 2) {
      const float* w2row = w2 + ((size_t)i * 384 + q) * 128;  // w2[i][q][.]
      const float* wfcol = wf + (size_t)128 * i * NCLS + c;
      for (int m = 0; m < 128; m++) val += w2row[m] * wfcol[m * NCLS];
    }
    Ut[(size_t)col * 384 + q] = (__bf16)val;
  } else {
    int c = tid;
    if (c < NCLS) {
      float s = bfv[c];
      for (int k = 0; k < 384; k++) s += b2[k] * wf[k * NCLS + c];
      cc[c] = s;
    }
  }
}

// ---- CSR build, single cooperative kernel: zero -> rank -> scan -> place ----
__global__ __launch_bounds__(256) void k_csr(
    const int* __restrict__ idx, const float* __restrict__ vals,
    int* __restrict__ cnt, int* __restrict__ rank,
    int* __restrict__ bsum, int* __restrict__ rowptr,
    int2* __restrict__ epack) {
  cg::grid_group grid = cg::this_grid();
  int tid = threadIdx.x;
  int lane = tid & 63;
  int t = blockIdx.x * 256 + tid;
  const int STRIDE = SCAN_NB * 256;  // 50176

  // phase 0: zero cnt
  if (t < N_NODES) cnt[t] = 0;
  grid.sync();

  // phase 1: histogram + per-edge rank (coalesced grid-stride)
  for (int e = t; e < N_EDGES; e += STRIDE)
    rank[e] = atomicAdd(&cnt[idx[e]], 1);
  grid.sync();

  // phase 2a: per-block sums
  int c = (t < N_NODES) ? cnt[t] : 0;
  {
    int v = c;
#pragma unroll
    for (int o = 32; o >= 1; o >>= 1) v += __shfl_down(v, o);
    __shared__ int ws[4];
    if (lane == 0) ws[tid >> 6] = v;
    __syncthreads();
    if (tid == 0) bsum[blockIdx.x] = ws[0] + ws[1] + ws[2] + ws[3];
  }
  grid.sync();

  // phase 2b: scan fill (inlined top-level scan of bsum)
  {
    int pv = (tid < (int)blockIdx.x && tid < SCAN_NB) ? bsum[tid] : 0;
#pragma unroll
    for (int o = 32; o >= 1; o >>= 1) pv += __shfl_down(pv, o);
    __shared__ int ps[4];
    if (lane == 0) ps[tid >> 6] = pv;
    int v = c;
#pragma unroll
    for (int o = 1; o < 64; o <<= 1) {
      int n = __shfl_up(v, o);
      if (lane >= o) v += n;
    }
    __shared__ int wt[4];
    if (lane == 63) wt[tid >> 6] = v;
    __syncthreads();
    int add = ps[0] + ps[1] + ps[2] + ps[3];
    for (int w = 0; w < (tid >> 6); w++) add += wt[w];
    int ex = v - c + add;
    if (t < N_NODES) rowptr[t] = ex;
    if (t == 0) rowptr[N_NODES] = N_EDGES;
  }
  grid.sync();

  // phase 3: place edges (atomic-free: pos = rowptr[r] + rank[e])
  for (int e = t; e < N_EDGES; e += STRIDE) {
    int r = idx[e];
    int cc2 = idx[N_EDGES + e];
    epack[rowptr[r] + rank[e]] = make_int2(cc2, __float_as_int(vals[e]));
  }
}

// --------- GEMM1: hb = relu(x @ w1 + b1), MFMA, fused fp32->bf16 cast --------
// XCD-aware trio mapping + 2-phase double-buffered LDS (one barrier/k-step).
// Best measured structure for this kernel (69.3 us, FETCH 53 MB).
#define G1_TRIOS 391           // ceil(50000/128)
#define G1_TPX 49              // trios per XCD (8*49 = 392 >= 391)
__global__ __launch_bounds__(256) void gemm1(
    const float* __restrict__ A,        // x [N,512] fp32
    const __bf16* __restrict__ Bt,      // w1t [3][128][512]
    const float* __restrict__ bias,     // [384]
    __bf16* __restrict__ hb) {          // [N,384]
  const int M = N_NODES, K = FIN;
  __shared__ __align__(16) __bf16 sA[2 * 128 * 32];
  __shared__ __align__(16) __bf16 sB[2 * 128 * 32];
  int tid = threadIdx.x;
  int id = blockIdx.x;
  int xcd = id & 7, slot = id >> 3;
  int trio = xcd * G1_TPX + slot / 3;
  int blk = slot - (slot / 3) * 3;
  if (trio >= G1_TRIOS) return;
  int m0 = trio * 128;
  const __bf16* Bblk = Bt + (size_t)blk * 128 * K;
  int wave = tid >> 6, lane = tid & 63;
  int wm = (wave & 1) * 64, wn = (wave >> 1) * 64;
  floatx4 acc[4][4] = {};

  int rA = lane >> 2;
  int gch = (lane & 3) ^ ((lane >> 3) & 3);
  int r0 = wave * 32 + rA;
  int r1 = r0 + 16;
  int gm0 = m0 + r0; gm0 = (gm0 < M) ? gm0 : (M - 1);
  int gm1 = m0 + r1; gm1 = (gm1 < M) ? gm1 : (M - 1);
  const float* pa0 = A + (size_t)gm0 * K + gch * 8;
  const float* pa1 = A + (size_t)gm1 * K + gch * 8;
  const __bf16* pb0 = Bblk + (size_t)r0 * K + gch * 8;
  const __bf16* pb1 = Bblk + (size_t)r1 * K + gch * 8;
  int lofsA = wave * 1024 + lane * 8;   // this thread's 16B LDS write slot
  int lofsB = wave * 1024;              // glds dest: wave-uniform base

  int fm = lane & 15, fg = lane >> 4;
  int sloto = (fg ^ ((fm >> 1) & 3)) * 8;

  // ---- prologue: stage k=0 into buffer 0 ----
  {
    floatx4 x0a = *(const floatx4*)(pa0);
    floatx4 x0b = *(const floatx4*)(pa0 + 4);
    floatx4 x1a = *(const floatx4*)(pa1);
    floatx4 x1b = *(const floatx4*)(pa1 + 4);
    glds16(pb0, sB + lofsB);
    glds16(pb1, sB + lofsB + 512);
    union { bf16x8 v; int4v i; } u0, u1;
#pragma unroll
    for (int q = 0; q < 4; q++) {
      u0.v[q] = (__bf16)x0a[q]; u0.v[q + 4] = (__bf16)x0b[q];
      u1.v[q] = (__bf16)x1a[q]; u1.v[q + 4] = (__bf16)x1b[q];
    }
    *(int4v*)(sA + lofsA) = u0.i;
    *(int4v*)(sA + lofsA + 512) = u1.i;
  }
  __syncthreads();

  // ---- main loop: compute buf(t&1), prefetch k(t+1) into buf(~t&1) ----
  for (int t = 0; t < 15; t++) {
    int cb = (t & 1) * 4096;
    int nb = cb ^ 4096;
    int k1 = t * 32 + 32;
    // issue next-step loads (async; latency hides under MFMA phase)
    floatx4 n0a = *(const floatx4*)(pa0 + k1);
    floatx4 n0b = *(const floatx4*)(pa0 + k1 + 4);
    floatx4 n1a = *(const floatx4*)(pa1 + k1);
    floatx4 n1b = *(const floatx4*)(pa1 + k1 + 4);
    glds16(pb0 + k1, sB + nb + lofsB);
    glds16(pb1 + k1, sB + nb + lofsB + 512);

    // compute current buffer
    bf16x8 af[4], bfr[4];
#pragma unroll
    for (int mt = 0; mt < 4; mt++)
      af[mt] = *(const bf16x8*)(sA + cb + (wm + mt * 16 + fm) * 32 + sloto);
#pragma unroll
    for (int nt = 0; nt < 4; nt++)
      bfr[nt] = *(const bf16x8*)(sB + cb + (wn + nt * 16 + fm) * 32 + sloto);
#pragma unroll
    for (int mt = 0; mt < 4; mt++)
#pragma unroll
      for (int nt = 0; nt < 4; nt++)
        acc[mt][nt] = __builtin_amdgcn_mfma_f32_16x16x32_bf16(af[mt], bfr[nt], acc[mt][nt], 0, 0, 0);

    // write next A tile (after MFMA so loads had time to land)
    union { bf16x8 v; int4v i; } u0, u1;
#pragma unroll
    for (int q = 0; q < 4; q++) {
      u0.v[q] = (__bf16)n0a[q]; u0.v[q + 4] = (__bf16)n0b[q];
      u1.v[q] = (__bf16)n1a[q]; u1.v[q + 4] = (__bf16)n1b[q];
    }
    *(int4v*)(sA + nb + lofsA) = u0.i;
    *(int4v*)(sA + nb + lofsA + 512) = u1.i;
    __syncthreads();  // drains glds (vmcnt) + ds_writes for buf nb
  }
  // ---- final k-step (t = 15, buffer 1) ----
  {
    int cb = 4096;
    bf16x8 af[4], bfr[4];
#pragma unroll
    for (int mt = 0; mt < 4; mt++)
      af[mt] = *(const bf16x8*)(sA + cb + (wm + mt * 16 + fm) * 32 + sloto);
#pragma unroll
    for (int nt = 0; nt < 4; nt++)
      bfr[nt] = *(const bf16x8*)(sB + cb + (wn + nt * 16 + fm) * 32 + sloto);
#pragma unroll
    for (int mt = 0; mt < 4; mt++)
#pragma unroll
      for (int nt = 0; nt < 4; nt++)
        acc[mt][nt] = __builtin_amdgcn_mfma_f32_16x16x32_bf16(af[mt], bfr[nt], acc[mt][nt], 0, 0, 0);
  }

  int colb = lane & 15, rbase = (lane >> 4) << 2;
#pragma unroll
  for (int mt = 0; mt < 4; mt++)
#pragma unroll
    for (int r = 0; r < 4; r++) {
      int gm = m0 + wm + mt * 16 + rbase + r;
      if (gm >= M) continue;
#pragma unroll
      for (int nt = 0; nt < 4; nt++) {
        int gc = blk * 128 + wn + nt * 16 + colb;
        float vv = acc[mt][nt][r] + bias[gc];
        vv = fmaxf(vv, 0.f);
        hb[(size_t)gm * 384 + gc] = (__bf16)vv;
      }
    }
}

// -------- S-GEMM: S[N,64] = hb@Ublk cols 0-63 (p=0..3); R4 = cols 64-79 ------
// Swapped-operand MFMA + 2 row-groups sharing B-frags (proven R6). NEW: XCD
// mapping matches gemm1's trio map, so each block's hb rows were written on
// the SAME XCD -> hb reads hit that XCD's L2 instead of HBM.
__global__ __launch_bounds__(256) void k_sgemm(
    const __bf16* __restrict__ hb,   // [N,384]
    const __bf16* __restrict__ Ut,   // [80,384]
    float* __restrict__ S,           // [N,64]  (p = 0..3)
    float* __restrict__ R4) {        // [N,16]  (p = 4)
  const int M = N_NODES;
  int id = blockIdx.x;
  int xcd = id & 7, slot = id >> 3;
  int trio = xcd * G1_TPX + slot;
  if (trio >= G1_TRIOS) return;
  int wave = threadIdx.x >> 6, lane = threadIdx.x & 63;
  int fm = lane & 15, fg = lane >> 4;
  int m0 = trio * 128 + wave * 32;
  floatx4 acc[2][5] = {};
  int r0 = m0 + fm;      r0 = (r0 < M) ? r0 : (M - 1);
  int r1 = m0 + 16 + fm; r1 = (r1 < M) ? r1 : (M - 1);
  const __bf16* pa0 = hb + (size_t)r0 * 384 + fg * 8;
  const __bf16* pa1 = hb + (size_t)r1 * 384 + fg * 8;
  const __bf16* pb  = Ut + (size_t)fm * 384 + fg * 8;
#pragma unroll 2
  for (int k0 = 0; k0 < 384; k0 += 32) {
    bf16x8 a0 = *(const bf16x8*)(pa0 + k0);
    bf16x8 a1 = *(const bf16x8*)(pa1 + k0);
#pragma unroll
    for (int nt = 0; nt < 5; nt++) {
      bf16x8 bv = *(const bf16x8*)(pb + (size_t)nt * 16 * 384 + k0);
      acc[0][nt] = __builtin_amdgcn_mfma_f32_16x16x32_bf16(bv, a0, acc[0][nt], 0, 0, 0);
      acc[1][nt] = __builtin_amdgcn_mfma_f32_16x16x32_bf16(bv, a1, acc[1][nt], 0, 0, 0);
    }
  }
  int gm0 = m0 + fm;
  if (gm0 < M) {
#pragma unroll
    for (int nt = 0; nt < 4; nt++)
      *(floatx4*)(S + (size_t)gm0 * 64 + nt * 16 + fg * 4) = acc[0][nt];
    *(floatx4*)(R4 + (size_t)gm0 * 16 + fg * 4) = acc[0][4];
  }
  int gm1 = m0 + 16 + fm;
  if (gm1 < M) {
#pragma unroll
    for (int nt = 0; nt < 4; nt++)
      *(floatx4*)(S + (size_t)gm1 * 64 + nt * 16 + fg * 4) = acc[1][nt];
    *(floatx4*)(R4 + (size_t)gm1 * 16 + fg * 4) = acc[1][4];
  }
}

// ---- Horner hop body: Rout = A@Rin + S_p; 4 lanes/row, float4/lane ---------
// (R7-proven structure.) Guarded, no early return (cooperative barriers).
template <bool FINAL>
__device__ __forceinline__ void hop_body(
    const int* __restrict__ rowptr, const int2* __restrict__ epack,
    const float* __restrict__ Rin, const float* __restrict__ S, int sofs,
    float* __restrict__ Rout, const float* __restrict__ cc) {
  int tid = threadIdx.x;
  int rg = tid >> 2, l = tid & 3;
  int row = blockIdx.x * 64 + rg;
  if (row < N_NODES) {
    int s = rowptr[row], e = rowptr[row + 1];
    floatx4 a = *(const floatx4*)(S + (size_t)row * 64 + sofs + l * 4);
    for (int i = s; i < e; i += 4) {
      int take = e - i; if (take > 4) take = 4;
      int2 ed = (l < take) ? epack[i + l] : make_int2(0, 0);
#pragma unroll
      for (int j = 0; j < 4; j++) {
        int c = __shfl(ed.x, j, 4);
        float v = __int_as_float(__shfl(ed.y, j, 4));
        floatx4 g = *(const floatx4*)(Rin + (size_t)c * 16 + l * 4);
        a += v * g;
      }
    }
    if (!FINAL) {
      *(floatx4*)(Rout + (size_t)row * 16 + l * 4) = a;
    } else {
      floatx4 ccv = *(const floatx4*)(cc + l * 4);
      a += ccv;
      float m = fmaxf(fmaxf(a[0], a[1]), fmaxf(a[2], a[3]));
      m = fmaxf(m, __shfl_xor(m, 1, 4));
      m = fmaxf(m, __shfl_xor(m, 2, 4));
      float sm = expf(a[0] - m) + expf(a[1] - m) + expf(a[2] - m) + expf(a[3] - m);
      sm += __shfl_xor(sm, 1, 4);
      sm += __shfl_xor(sm, 2, 4);
      float ls = logf(sm);
      floatx4 o;
#pragma unroll
      for (int q = 0; q < 4; q++) o[q] = (a[q] - m) - ls;
      *(floatx4*)(Rout + (size_t)row * 16 + l * 4) = o;
    }
  }
}

// ---- All 4 Horner hops in one cooperative kernel (grid.sync between) -------
__global__ __launch_bounds__(256) void k_hops(
    const int* __restrict__ rowptr, const int2* __restrict__ epack,
    const float* __restrict__ R4, const float* __restrict__ S,
    float* __restrict__ RA, float* __restrict__ RB,
    float* __restrict__ out, const float* __restrict__ cc) {
  cg::grid_group grid = cg::this_grid();
  hop_body<false>(rowptr, epack, R4, S, 48, RB, cc);
  grid.sync();
  hop_body<false>(rowptr, epack, RB, S, 32, RA, cc);
  grid.sync();
  hop_body<false>(rowptr, epack, RA, S, 16, RB, cc);
  grid.sync();
  hop_body<true>(rowptr, epack, RB, S, 0, out, cc);
}

// ---------------- launch ----------------
extern "C" void kernel_launch(void* const* d_in, const int* in_sizes, int n_in,
                              void* d_out, int out_size, void* d_ws, size_t ws_size,
                              hipStream_t stream) {
  const float* x   = (const float*)d_in[0];
  const int*   adj = (const int*)d_in[1];
  const float* av  = (const float*)d_in[2];
  const float* w1  = (const float*)d_in[3];
  const float* b1  = (const float*)d_in[4];
  const float* w2  = (const float*)d_in[5];
  const float* b2  = (const float*)d_in[6];
  const float* wf  = (const float*)d_in[7];
  const float* bf  = (const float*)d_in[8];
  float* out = (float*)d_out;

  char* ws = (char*)d_ws;
  size_t off = 0;
  auto alloc = [&](size_t bytes) -> void* {
    off = (off + 255) & ~(size_t)255;
    void* p = ws + off;
    off += bytes;
    return p;
  };

  float* S    = (float*)alloc((size_t)N_NODES * 64 * 4);   // [N,64]
  float* R4   = (float*)alloc((size_t)N_NODES * 16 * 4);
  float* RA   = (float*)alloc((size_t)N_NODES * 16 * 4);
  float* RB   = (float*)alloc((size_t)N_NODES * 16 * 4);
  __bf16* hb  = (__bf16*)alloc((size_t)N_NODES * 384 * 2);
  __bf16* w1t = (__bf16*)alloc((size_t)3 * 128 * FIN * 2);
  __bf16* Ut  = (__bf16*)alloc((size_t)80 * 384 * 2);
  int* rowptr = (int*)alloc((size_t)(N_NODES + 1) * 4);
  int* cnt    = (int*)alloc((size_t)N_NODES * 4);
  int* bsum   = (int*)alloc((size_t)SCAN_NB * 4);
  int* rankv  = (int*)alloc((size_t)N_EDGES * 4);
  int2* epack = (int2*)alloc((size_t)N_EDGES * 8);
  float* cc   = (float*)alloc(64);

  // prep (independent of CSR)
  k_prep<<<PREP_NT1 + PREP_NU + 1, 256, 0, stream>>>(
      w1, w1t, w2, wf, Ut, b2, bf, cc);

  // CSR build: one cooperative kernel (zero -> rank -> scan -> place)
  {
    void* args[] = {(void*)&adj, (void*)&av, (void*)&cnt, (void*)&rankv,
                    (void*)&bsum, (void*)&rowptr, (void*)&epack};
    hipLaunchCooperativeKernel((void*)k_csr, dim3(SCAN_NB), dim3(256),
                               args, 0, stream);
  }

  // GEMM1: hb = relu(x@w1 + b1)  [N,384] bf16
  gemm1<<<8 * G1_TPX * 3, 256, 0, stream>>>(x, w1t, b1, hb);

  // S-GEMM: S[N,64] (p=0..3) + R4[N,16] (p=4), XCD-matched to gemm1
  k_sgemm<<<8 * G1_TPX, 256, 0, stream>>>(hb, Ut, S, R4);

  // Horner chain: one cooperative kernel, 4 phases
  {
    void* hargs[] = {(void*)&rowptr, (void*)&epack, (void*)&R4, (void*)&S,
                     (void*)&RA, (void*)&RB, (void*)&out, (void*)&cc};
    hipLaunchCooperativeKernel((void*)k_hops, dim3((N_NODES + 63) / 64),
                               dim3(256), hargs, 0, stream);
  }
}

// Round 9
// 345.737 us; speedup vs baseline: 2.0002x; 2.0002x over previous
//
#include <hip/hip_runtime.h>
#include <hip/hip_bf16.h>
#include <cstdint>
#include <cstddef>

#define N_NODES 50000
#define N_EDGES 800000
#define FIN 512
#define HW_ 128
#define NCLS 16
#define SCAN_NB 196  // ceil(50000/256)

typedef __attribute__((ext_vector_type(4))) float floatx4;
typedef __attribute__((ext_vector_type(4))) int int4v;
typedef __bf16 bf16x8 __attribute__((ext_vector_type(8)));

__device__ __forceinline__ void glds16(const __bf16* g, __bf16* l) {
  __builtin_amdgcn_global_load_lds(
      (const __attribute__((address_space(1))) void*)g,
      (__attribute__((address_space(3))) void*)l, 16, 0, 0);
}

__device__ __forceinline__ int2 ldnt_int2(const int2* p) {
  long long v = __builtin_nontemporal_load((const long long*)p);
  int2 r;
  r.x = (int)(v & 0xffffffffLL);
  r.y = (int)(v >> 32);
  return r;
}

// ------- fused: rank (hist + per-edge rank) | w1 transpose | U=w2@wf | constc
// Ut[80][384] bf16: Ut[16p+c][128j+r] = U_{(p-j) j}[r][c] (0 if p-j not in 0..2)
#define RP_NRANK 782           // ceil(800000/1024)
#define PREP_NT1 48            // 3 * (512/64) * (128/64)
#define PREP_NU 120            // 80*384 / 256
__global__ __launch_bounds__(256) void k_rank_prep(
    const int* __restrict__ idx, int* __restrict__ cnt, int* __restrict__ rank,
    const float* __restrict__ w1, __bf16* __restrict__ w1t,
    const float* __restrict__ w2, const float* __restrict__ wf,
    __bf16* __restrict__ Ut,
    const float* __restrict__ b2, const float* __restrict__ bfv,
    float* __restrict__ cc) {
  int b = blockIdx.x;
  int tid = threadIdx.x;
  if (b < RP_NRANK) {
    int e = b * 1024 + tid;
#pragma unroll
    for (int u = 0; u < 4; u++) {
      int ee = e + u * 256;
      if (ee < N_EDGES) rank[ee] = atomicAdd(&cnt[idx[ee]], 1);
    }
  } else if (b < RP_NRANK + PREP_NT1) {
    // 64x64 tile transpose: w1[K][128] -> w1t[128][K], fp32 -> bf16
    int tb = b - RP_NRANK;
    const int K = FIN;
    int tilesK = K >> 6;
    int i = tb / (tilesK * 2);
    int rr = tb - i * tilesK * 2;
    int kt = rr >> 1;
    int nt = rr & 1;
    const float* wS = w1 + (size_t)i * K * 128;
    __bf16* wtS = w1t + (size_t)i * 128 * K;
    int k0 = kt * 64, n0 = nt * 64;
    __shared__ float tile[64][65];
    int tc = tid & 63, tr = tid >> 6;
#pragma unroll
    for (int q = 0; q < 16; q++) {
      int row = tr + q * 4;
      tile[row][tc] = wS[(size_t)(k0 + row) * 128 + n0 + tc];
    }
    __syncthreads();
#pragma unroll
    for (int q = 0; q < 16; q++) {
      int nr = tr + q * 4;
      wtS[(size_t)(n0 + nr) * K + k0 + tc] = (__bf16)tile[tc][nr];
    }
  } else if (b < RP_NRANK + PREP_NT1 + PREP_NU) {
    int t = (b - RP_NRANK - PREP_NT1) * 256 + tid;  // [0, 30720)
    int col = t / 384;            // 0..79 = 16p + c
    int q = t - col * 384;        // 0..383 = 128j + r
    int p = col >> 4, c = col & 15;
    int j = q >> 7;
    int i = p - j;
    float val = 0.f;
    if (i >= 0 && i <= 2) {
      const float* w2row = w2 + ((size_t)i * 384 + q) * 128;  // w2[i][q][.]
      const float* wfcol = wf + (size_t)128 * i * NCLS + c;
      for (int m = 0; m < 128; m++) val += w2row[m] * wfcol[m * NCLS];
    }
    Ut[(size_t)col * 384 + q] = (__bf16)val;
  } else {
    int c = tid;
    if (c < NCLS) {
      float s = bfv[c];
      for (int k = 0; k < 384; k++) s += b2[k] * wf[k * NCLS + c];
      cc[c] = s;
    }
  }
}

// ---------------- parallel scan: per-block sums ----------------
__global__ __launch_bounds__(256) void k_scan_block(const int* __restrict__ cnt,
                                                    int* __restrict__ bsum) {
  int t = blockIdx.x * 256 + threadIdx.x;
  int v = (t < N_NODES) ? cnt[t] : 0;
#pragma unroll
  for (int o = 32; o >= 1; o >>= 1) v += __shfl_down(v, o);
  __shared__ int ws[4];
  if ((threadIdx.x & 63) == 0) ws[threadIdx.x >> 6] = v;
  __syncthreads();
  if (threadIdx.x == 0) bsum[blockIdx.x] = ws[0] + ws[1] + ws[2] + ws[3];
}

// ---------------- scan fill (inlines top-level scan of bsum) ----------------
__global__ __launch_bounds__(256) void k_scan_fill(const int* __restrict__ cnt,
                                                   const int* __restrict__ bsum,
                                                   int* __restrict__ rowptr) {
  int tid = threadIdx.x;
  int lane = tid & 63;
  int pv = (tid < blockIdx.x && tid < SCAN_NB) ? bsum[tid] : 0;
#pragma unroll
  for (int o = 32; o >= 1; o >>= 1) pv += __shfl_down(pv, o);
  __shared__ int ps[4];
  if (lane == 0) ps[tid >> 6] = pv;
  int t = blockIdx.x * 256 + tid;
  int c = (t < N_NODES) ? cnt[t] : 0;
  int v = c;
#pragma unroll
  for (int o = 1; o < 64; o <<= 1) {
    int n = __shfl_up(v, o);
    if (lane >= o) v += n;
  }
  __shared__ int wt[4];
  if (lane == 63) wt[tid >> 6] = v;
  __syncthreads();
  int add = ps[0] + ps[1] + ps[2] + ps[3];
  for (int w = 0; w < (tid >> 6); w++) add += wt[w];
  int ex = v - c + add;
  if (t < N_NODES) rowptr[t] = ex;
  if (t == 0) rowptr[N_NODES] = N_EDGES;
}

// ---------------- place edges (atomic-free: pos = rowptr[r] + rank[e]) -------
__global__ __launch_bounds__(256) void k_place(
    const int* __restrict__ idx, const float* __restrict__ vals,
    const int* __restrict__ rank, const int* __restrict__ rowptr,
    int2* __restrict__ epack) {
  int e = blockIdx.x * 256 + threadIdx.x;
  if (e < N_EDGES) {
    int r = idx[e];
    int c = idx[N_EDGES + e];
    int p = rowptr[r] + rank[e];
    epack[p] = make_int2(c, __float_as_int(vals[e]));
  }
}

// --------- GEMM1: hb = relu(x @ w1 + b1), MFMA, fused fp32->bf16 cast --------
// XCD-aware trio mapping + 2-phase double-buffered LDS (one barrier/k-step).
// Best measured structure for this kernel (69.3 us, FETCH 53 MB).
#define G1_TRIOS 391           // ceil(50000/128)
#define G1_TPX 49              // trios per XCD (8*49 = 392 >= 391)
__global__ __launch_bounds__(256) void gemm1(
    const float* __restrict__ A,        // x [N,512] fp32
    const __bf16* __restrict__ Bt,      // w1t [3][128][512]
    const float* __restrict__ bias,     // [384]
    __bf16* __restrict__ hb) {          // [N,384]
  const int M = N_NODES, K = FIN;
  __shared__ __align__(16) __bf16 sA[2 * 128 * 32];
  __shared__ __align__(16) __bf16 sB[2 * 128 * 32];
  int tid = threadIdx.x;
  int id = blockIdx.x;
  int xcd = id & 7, slot = id >> 3;
  int trio = xcd * G1_TPX + slot / 3;
  int blk = slot - (slot / 3) * 3;
  if (trio >= G1_TRIOS) return;
  int m0 = trio * 128;
  const __bf16* Bblk = Bt + (size_t)blk * 128 * K;
  int wave = tid >> 6, lane = tid & 63;
  int wm = (wave & 1) * 64, wn = (wave >> 1) * 64;
  floatx4 acc[4][4] = {};

  int rA = lane >> 2;
  int gch = (lane & 3) ^ ((lane >> 3) & 3);
  int r0 = wave * 32 + rA;
  int r1 = r0 + 16;
  int gm0 = m0 + r0; gm0 = (gm0 < M) ? gm0 : (M - 1);
  int gm1 = m0 + r1; gm1 = (gm1 < M) ? gm1 : (M - 1);
  const float* pa0 = A + (size_t)gm0 * K + gch * 8;
  const float* pa1 = A + (size_t)gm1 * K + gch * 8;
  const __bf16* pb0 = Bblk + (size_t)r0 * K + gch * 8;
  const __bf16* pb1 = Bblk + (size_t)r1 * K + gch * 8;
  int lofsA = wave * 1024 + lane * 8;   // this thread's 16B LDS write slot
  int lofsB = wave * 1024;              // glds dest: wave-uniform base

  int fm = lane & 15, fg = lane >> 4;
  int sloto = (fg ^ ((fm >> 1) & 3)) * 8;

  // ---- prologue: stage k=0 into buffer 0 ----
  {
    floatx4 x0a = *(const floatx4*)(pa0);
    floatx4 x0b = *(const floatx4*)(pa0 + 4);
    floatx4 x1a = *(const floatx4*)(pa1);
    floatx4 x1b = *(const floatx4*)(pa1 + 4);
    glds16(pb0, sB + lofsB);
    glds16(pb1, sB + lofsB + 512);
    union { bf16x8 v; int4v i; } u0, u1;
#pragma unroll
    for (int q = 0; q < 4; q++) {
      u0.v[q] = (__bf16)x0a[q]; u0.v[q + 4] = (__bf16)x0b[q];
      u1.v[q] = (__bf16)x1a[q]; u1.v[q + 4] = (__bf16)x1b[q];
    }
    *(int4v*)(sA + lofsA) = u0.i;
    *(int4v*)(sA + lofsA + 512) = u1.i;
  }
  __syncthreads();

  // ---- main loop: compute buf(t&1), prefetch k(t+1) into buf(~t&1) ----
  for (int t = 0; t < 15; t++) {
    int cb = (t & 1) * 4096;
    int nb = cb ^ 4096;
    int k1 = t * 32 + 32;
    // issue next-step loads (async; latency hides under MFMA phase)
    floatx4 n0a = *(const floatx4*)(pa0 + k1);
    floatx4 n0b = *(const floatx4*)(pa0 + k1 + 4);
    floatx4 n1a = *(const floatx4*)(pa1 + k1);
    floatx4 n1b = *(const floatx4*)(pa1 + k1 + 4);
    glds16(pb0 + k1, sB + nb + lofsB);
    glds16(pb1 + k1, sB + nb + lofsB + 512);

    // compute current buffer
    bf16x8 af[4], bfr[4];
#pragma unroll
    for (int mt = 0; mt < 4; mt++)
      af[mt] = *(const bf16x8*)(sA + cb + (wm + mt * 16 + fm) * 32 + sloto);
#pragma unroll
    for (int nt = 0; nt < 4; nt++)
      bfr[nt] = *(const bf16x8*)(sB + cb + (wn + nt * 16 + fm) * 32 + sloto);
#pragma unroll
    for (int mt = 0; mt < 4; mt++)
#pragma unroll
      for (int nt = 0; nt < 4; nt++)
        acc[mt][nt] = __builtin_amdgcn_mfma_f32_16x16x32_bf16(af[mt], bfr[nt], acc[mt][nt], 0, 0, 0);

    // write next A tile (after MFMA so loads had time to land)
    union { bf16x8 v; int4v i; } u0, u1;
#pragma unroll
    for (int q = 0; q < 4; q++) {
      u0.v[q] = (__bf16)n0a[q]; u0.v[q + 4] = (__bf16)n0b[q];
      u1.v[q] = (__bf16)n1a[q]; u1.v[q + 4] = (__bf16)n1b[q];
    }
    *(int4v*)(sA + nb + lofsA) = u0.i;
    *(int4v*)(sA + nb + lofsA + 512) = u1.i;
    __syncthreads();  // drains glds (vmcnt) + ds_writes for buf nb
  }
  // ---- final k-step (t = 15, buffer 1) ----
  {
    int cb = 4096;
    bf16x8 af[4], bfr[4];
#pragma unroll
    for (int mt = 0; mt < 4; mt++)
      af[mt] = *(const bf16x8*)(sA + cb + (wm + mt * 16 + fm) * 32 + sloto);
#pragma unroll
    for (int nt = 0; nt < 4; nt++)
      bfr[nt] = *(const bf16x8*)(sB + cb + (wn + nt * 16 + fm) * 32 + sloto);
#pragma unroll
    for (int mt = 0; mt < 4; mt++)
#pragma unroll
      for (int nt = 0; nt < 4; nt++)
        acc[mt][nt] = __builtin_amdgcn_mfma_f32_16x16x32_bf16(af[mt], bfr[nt], acc[mt][nt], 0, 0, 0);
  }

  int colb = lane & 15, rbase = (lane >> 4) << 2;
#pragma unroll
  for (int mt = 0; mt < 4; mt++)
#pragma unroll
    for (int r = 0; r < 4; r++) {
      int gm = m0 + wm + mt * 16 + rbase + r;
      if (gm >= M) continue;
#pragma unroll
      for (int nt = 0; nt < 4; nt++) {
        int gc = blk * 128 + wn + nt * 16 + colb;
        float vv = acc[mt][nt][r] + bias[gc];
        vv = fmaxf(vv, 0.f);
        hb[(size_t)gm * 384 + gc] = (__bf16)vv;
      }
    }
}

// -------- S-GEMM: S[N,64] = hb@Ublk cols 0-63 (p=0..3); R4 = cols 64-79 ------
// Swapped-operand MFMA + 2 row-groups sharing B-frags (proven R6). XCD
// mapping matches gemm1's trio map, so each block's hb rows were written on
// the SAME XCD -> hb reads hit that XCD's L2 instead of HBM.
__global__ __launch_bounds__(256) void k_sgemm(
    const __bf16* __restrict__ hb,   // [N,384]
    const __bf16* __restrict__ Ut,   // [80,384]
    float* __restrict__ S,           // [N,64]  (p = 0..3)
    float* __restrict__ R4) {        // [N,16]  (p = 4)
  const int M = N_NODES;
  int id = blockIdx.x;
  int xcd = id & 7, slot = id >> 3;
  int trio = xcd * G1_TPX + slot;
  if (trio >= G1_TRIOS) return;
  int wave = threadIdx.x >> 6, lane = threadIdx.x & 63;
  int fm = lane & 15, fg = lane >> 4;
  int m0 = trio * 128 + wave * 32;
  floatx4 acc[2][5] = {};
  int r0 = m0 + fm;      r0 = (r0 < M) ? r0 : (M - 1);
  int r1 = m0 + 16 + fm; r1 = (r1 < M) ? r1 : (M - 1);
  const __bf16* pa0 = hb + (size_t)r0 * 384 + fg * 8;
  const __bf16* pa1 = hb + (size_t)r1 * 384 + fg * 8;
  const __bf16* pb  = Ut + (size_t)fm * 384 + fg * 8;
#pragma unroll 2
  for (int k0 = 0; k0 < 384; k0 += 32) {
    bf16x8 a0 = *(const bf16x8*)(pa0 + k0);
    bf16x8 a1 = *(const bf16x8*)(pa1 + k0);
#pragma unroll
    for (int nt = 0; nt < 5; nt++) {
      bf16x8 bv = *(const bf16x8*)(pb + (size_t)nt * 16 * 384 + k0);
      acc[0][nt] = __builtin_amdgcn_mfma_f32_16x16x32_bf16(bv, a0, acc[0][nt], 0, 0, 0);
      acc[1][nt] = __builtin_amdgcn_mfma_f32_16x16x32_bf16(bv, a1, acc[1][nt], 0, 0, 0);
    }
  }
  int gm0 = m0 + fm;
  if (gm0 < M) {
#pragma unroll
    for (int nt = 0; nt < 4; nt++)
      *(floatx4*)(S + (size_t)gm0 * 64 + nt * 16 + fg * 4) = acc[0][nt];
    *(floatx4*)(R4 + (size_t)gm0 * 16 + fg * 4) = acc[0][4];
  }
  int gm1 = m0 + 16 + fm;
  if (gm1 < M) {
#pragma unroll
    for (int nt = 0; nt < 4; nt++)
      *(floatx4*)(S + (size_t)gm1 * 64 + nt * 16 + fg * 4) = acc[1][nt];
    *(floatx4*)(R4 + (size_t)gm1 * 16 + fg * 4) = acc[1][4];
  }
}

// ---- Horner hop: Rout = A@Rin + S_p; 4 lanes/row, float4/lane -------------
// R7-proven structure + (a) nontemporal epack loads (streaming, keeps Rin
// L2-resident), (b) next-chunk ed prefetch so the edge-list load latency
// hides under the current chunk's 4 gathers + FMAs.
template <bool FINAL>
__global__ __launch_bounds__(256) void k_hop(
    const int* __restrict__ rowptr, const int2* __restrict__ epack,
    const float* __restrict__ Rin,      // [N,16]
    const float* __restrict__ S, int sofs,  // S + row*64 + sofs
    float* __restrict__ Rout,           // [N,16] (or out)
    const float* __restrict__ cc) {
  int tid = threadIdx.x;
  int rg = tid >> 2, l = tid & 3;
  int row = blockIdx.x * 64 + rg;
  if (row >= N_NODES) return;
  int s = rowptr[row], e = rowptr[row + 1];
  floatx4 a = *(const floatx4*)(S + (size_t)row * 64 + sofs + l * 4);
  int2 ed = make_int2(0, 0);
  if (s + l < e) ed = ldnt_int2(&epack[s + l]);
  for (int i = s; i < e; i += 4) {
    int2 cur = ed;
    int ni = i + 4;
    ed = make_int2(0, 0);
    if (ni + l < e) ed = ldnt_int2(&epack[ni + l]);  // prefetch next chunk
#pragma unroll
    for (int j = 0; j < 4; j++) {
      int c = __shfl(cur.x, j, 4);
      float v = __int_as_float(__shfl(cur.y, j, 4));
      floatx4 g = *(const floatx4*)(Rin + (size_t)c * 16 + l * 4);
      a += v * g;
    }
  }
  if (!FINAL) {
    *(floatx4*)(Rout + (size_t)row * 16 + l * 4) = a;
  } else {
    floatx4 ccv = *(const floatx4*)(cc + l * 4);
    a += ccv;
    float m = fmaxf(fmaxf(a[0], a[1]), fmaxf(a[2], a[3]));
    m = fmaxf(m, __shfl_xor(m, 1, 4));
    m = fmaxf(m, __shfl_xor(m, 2, 4));
    float sm = expf(a[0] - m) + expf(a[1] - m) + expf(a[2] - m) + expf(a[3] - m);
    sm += __shfl_xor(sm, 1, 4);
    sm += __shfl_xor(sm, 2, 4);
    float ls = logf(sm);
    floatx4 o;
#pragma unroll
    for (int q = 0; q < 4; q++) o[q] = (a[q] - m) - ls;
    *(floatx4*)(Rout + (size_t)row * 16 + l * 4) = o;
  }
}

// ---------------- launch ----------------
extern "C" void kernel_launch(void* const* d_in, const int* in_sizes, int n_in,
                              void* d_out, int out_size, void* d_ws, size_t ws_size,
                              hipStream_t stream) {
  const float* x   = (const float*)d_in[0];
  const int*   adj = (const int*)d_in[1];
  const float* av  = (const float*)d_in[2];
  const float* w1  = (const float*)d_in[3];
  const float* b1  = (const float*)d_in[4];
  const float* w2  = (const float*)d_in[5];
  const float* b2  = (const float*)d_in[6];
  const float* wf  = (const float*)d_in[7];
  const float* bf  = (const float*)d_in[8];
  float* out = (float*)d_out;

  char* ws = (char*)d_ws;
  size_t off = 0;
  auto alloc = [&](size_t bytes) -> void* {
    off = (off + 255) & ~(size_t)255;
    void* p = ws + off;
    off += bytes;
    return p;
  };

  float* S    = (float*)alloc((size_t)N_NODES * 64 * 4);   // [N,64]
  float* R4   = (float*)alloc((size_t)N_NODES * 16 * 4);
  float* RA   = (float*)alloc((size_t)N_NODES * 16 * 4);
  float* RB   = (float*)alloc((size_t)N_NODES * 16 * 4);
  __bf16* hb  = (__bf16*)alloc((size_t)N_NODES * 384 * 2);
  __bf16* w1t = (__bf16*)alloc((size_t)3 * 128 * FIN * 2);
  __bf16* Ut  = (__bf16*)alloc((size_t)80 * 384 * 2);
  int* rowptr = (int*)alloc((size_t)(N_NODES + 1) * 4);
  int* cnt    = (int*)alloc((size_t)N_NODES * 4);
  int* bsum   = (int*)alloc((size_t)SCAN_NB * 4);
  int* rankv  = (int*)alloc((size_t)N_EDGES * 4);
  int2* epack = (int2*)alloc((size_t)N_EDGES * 8);
  float* cc   = (float*)alloc(64);

  // CSR build (atomic-free placement) + prep, rank+prep fused
  hipMemsetAsync(cnt, 0, (size_t)N_NODES * 4, stream);
  k_rank_prep<<<RP_NRANK + PREP_NT1 + PREP_NU + 1, 256, 0, stream>>>(
      adj, cnt, rankv, w1, w1t, w2, wf, Ut, b2, bf, cc);
  k_scan_block<<<SCAN_NB, 256, 0, stream>>>(cnt, bsum);
  k_scan_fill<<<SCAN_NB, 256, 0, stream>>>(cnt, bsum, rowptr);
  k_place<<<(N_EDGES + 255) / 256, 256, 0, stream>>>(adj, av, rankv, rowptr, epack);

  // GEMM1: hb = relu(x@w1 + b1)  [N,384] bf16
  gemm1<<<8 * G1_TPX * 3, 256, 0, stream>>>(x, w1t, b1, hb);

  // S-GEMM: S[N,64] (p=0..3) + R4[N,16] (p=4), XCD-matched to gemm1
  k_sgemm<<<8 * G1_TPX, 256, 0, stream>>>(hb, Ut, S, R4);

  // Horner: R = S_p + A*R, p = 3,2,1,0 (last fused with +const and log_softmax)
  int hop_grid = (N_NODES + 63) / 64;
  k_hop<false><<<hop_grid, 256, 0, stream>>>(rowptr, epack, R4, S, 48, RB, cc);
  k_hop<false><<<hop_grid, 256, 0, stream>>>(rowptr, epack, RB, S, 32, RA, cc);
  k_hop<false><<<hop_grid, 256, 0, stream>>>(rowptr, epack, RA, S, 16, RB, cc);
  k_hop<true><<<hop_grid, 256, 0, stream>>>(rowptr, epack, RB, S, 0, out, cc);
}

// Round 10
// 329.527 us; speedup vs baseline: 2.0986x; 1.0492x over previous
//
#include <hip/hip_runtime.h>
#include <hip/hip_bf16.h>
#include <cstdint>
#include <cstddef>

#define N_NODES 50000
#define N_EDGES 800000
#define FIN 512
#define HW_ 128
#define NCLS 16
#define SCAN_NB 196  // ceil(50000/256)

typedef __attribute__((ext_vector_type(4))) float floatx4;
typedef __attribute__((ext_vector_type(4))) int int4v;
typedef __bf16 bf16x8 __attribute__((ext_vector_type(8)));

__device__ __forceinline__ void glds16(const __bf16* g, __bf16* l) {
  __builtin_amdgcn_global_load_lds(
      (const __attribute__((address_space(1))) void*)g,
      (__attribute__((address_space(3))) void*)l, 16, 0, 0);
}

// ------- fused: rank (hist + per-edge rank) | w1 transpose | U=w2@wf | constc
// Ut[80][384] bf16: Ut[16p+c][128j+r] = U_{(p-j) j}[r][c] (0 if p-j not in 0..2)
#define RP_NRANK 782           // ceil(800000/1024)
#define PREP_NT1 48            // 3 * (512/64) * (128/64)
#define PREP_NU 120            // 80*384 / 256
__global__ __launch_bounds__(256) void k_rank_prep(
    const int* __restrict__ idx, int* __restrict__ cnt, int* __restrict__ rank,
    const float* __restrict__ w1, __bf16* __restrict__ w1t,
    const float* __restrict__ w2, const float* __restrict__ wf,
    __bf16* __restrict__ Ut,
    const float* __restrict__ b2, const float* __restrict__ bfv,
    float* __restrict__ cc) {
  int b = blockIdx.x;
  int tid = threadIdx.x;
  if (b < RP_NRANK) {
    int e = b * 1024 + tid;
#pragma unroll
    for (int u = 0; u < 4; u++) {
      int ee = e + u * 256;
      if (ee < N_EDGES) rank[ee] = atomicAdd(&cnt[idx[ee]], 1);
    }
  } else if (b < RP_NRANK + PREP_NT1) {
    // 64x64 tile transpose: w1[K][128] -> w1t[128][K], fp32 -> bf16
    int tb = b - RP_NRANK;
    const int K = FIN;
    int tilesK = K >> 6;
    int i = tb / (tilesK * 2);
    int rr = tb - i * tilesK * 2;
    int kt = rr >> 1;
    int nt = rr & 1;
    const float* wS = w1 + (size_t)i * K * 128;
    __bf16* wtS = w1t + (size_t)i * 128 * K;
    int k0 = kt * 64, n0 = nt * 64;
    __shared__ float tile[64][65];
    int tc = tid & 63, tr = tid >> 6;
#pragma unroll
    for (int q = 0; q < 16; q++) {
      int row = tr + q * 4;
      tile[row][tc] = wS[(size_t)(k0 + row) * 128 + n0 + tc];
    }
    __syncthreads();
#pragma unroll
    for (int q = 0; q < 16; q++) {
      int nr = tr + q * 4;
      wtS[(size_t)(n0 + nr) * K + k0 + tc] = (__bf16)tile[tc][nr];
    }
  } else if (b < RP_NRANK + PREP_NT1 + PREP_NU) {
    int t = (b - RP_NRANK - PREP_NT1) * 256 + tid;  // [0, 30720)
    int col = t / 384;            // 0..79 = 16p + c
    int q = t - col * 384;        // 0..383 = 128j + r
    int p = col >> 4, c = col & 15;
    int j = q >> 7;
    int i = p - j;
    float val = 0.f;
    if (i >= 0 && i <= 2) {
      const float* w2row = w2 + ((size_t)i * 384 + q) * 128;  // w2[i][q][.]
      const float* wfcol = wf + (size_t)128 * i * NCLS + c;
      for (int m = 0; m < 128; m++) val += w2row[m] * wfcol[m * NCLS];
    }
    Ut[(size_t)col * 384 + q] = (__bf16)val;
  } else {
    int c = tid;
    if (c < NCLS) {
      float s = bfv[c];
      for (int k = 0; k < 384; k++) s += b2[k] * wf[k * NCLS + c];
      cc[c] = s;
    }
  }
}

// ---------------- parallel scan: per-block sums ----------------
__global__ __launch_bounds__(256) void k_scan_block(const int* __restrict__ cnt,
                                                    int* __restrict__ bsum) {
  int t = blockIdx.x * 256 + threadIdx.x;
  int v = (t < N_NODES) ? cnt[t] : 0;
#pragma unroll
  for (int o = 32; o >= 1; o >>= 1) v += __shfl_down(v, o);
  __shared__ int ws[4];
  if ((threadIdx.x & 63) == 0) ws[threadIdx.x >> 6] = v;
  __syncthreads();
  if (threadIdx.x == 0) bsum[blockIdx.x] = ws[0] + ws[1] + ws[2] + ws[3];
}

// ---------------- scan fill (inlines top-level scan of bsum) ----------------
__global__ __launch_bounds__(256) void k_scan_fill(const int* __restrict__ cnt,
                                                   const int* __restrict__ bsum,
                                                   int* __restrict__ rowptr) {
  int tid = threadIdx.x;
  int lane = tid & 63;
  int pv = (tid < blockIdx.x && tid < SCAN_NB) ? bsum[tid] : 0;
#pragma unroll
  for (int o = 32; o >= 1; o >>= 1) pv += __shfl_down(pv, o);
  __shared__ int ps[4];
  if (lane == 0) ps[tid >> 6] = pv;
  int t = blockIdx.x * 256 + tid;
  int c = (t < N_NODES) ? cnt[t] : 0;
  int v = c;
#pragma unroll
  for (int o = 1; o < 64; o <<= 1) {
    int n = __shfl_up(v, o);
    if (lane >= o) v += n;
  }
  __shared__ int wt[4];
  if (lane == 63) wt[tid >> 6] = v;
  __syncthreads();
  int add = ps[0] + ps[1] + ps[2] + ps[3];
  for (int w = 0; w < (tid >> 6); w++) add += wt[w];
  int ex = v - c + add;
  if (t < N_NODES) rowptr[t] = ex;
  if (t == 0) rowptr[N_NODES] = N_EDGES;
}

// ---------------- place edges (atomic-free: pos = rowptr[r] + rank[e]) -------
__global__ __launch_bounds__(256) void k_place(
    const int* __restrict__ idx, const float* __restrict__ vals,
    const int* __restrict__ rank, const int* __restrict__ rowptr,
    int2* __restrict__ epack) {
  int e = blockIdx.x * 256 + threadIdx.x;
  if (e < N_EDGES) {
    int r = idx[e];
    int c = idx[N_EDGES + e];
    int p = rowptr[r] + rank[e];
    epack[p] = make_int2(c, __float_as_int(vals[e]));
  }
}

// --------- GEMM1: hb = relu(x @ w1 + b1), MFMA, fused fp32->bf16 cast --------
// XCD-aware trio mapping + 2-phase double-buffered LDS (one barrier/k-step).
// Best measured structure for this kernel (69.3 us, FETCH 53 MB).
#define G1_TRIOS 391           // ceil(50000/128)
#define G1_TPX 49              // trios per XCD (8*49 = 392 >= 391)
__global__ __launch_bounds__(256) void gemm1(
    const float* __restrict__ A,        // x [N,512] fp32
    const __bf16* __restrict__ Bt,      // w1t [3][128][512]
    const float* __restrict__ bias,     // [384]
    __bf16* __restrict__ hb) {          // [N,384]
  const int M = N_NODES, K = FIN;
  __shared__ __align__(16) __bf16 sA[2 * 128 * 32];
  __shared__ __align__(16) __bf16 sB[2 * 128 * 32];
  int tid = threadIdx.x;
  int id = blockIdx.x;
  int xcd = id & 7, slot = id >> 3;
  int trio = xcd * G1_TPX + slot / 3;
  int blk = slot - (slot / 3) * 3;
  if (trio >= G1_TRIOS) return;
  int m0 = trio * 128;
  const __bf16* Bblk = Bt + (size_t)blk * 128 * K;
  int wave = tid >> 6, lane = tid & 63;
  int wm = (wave & 1) * 64, wn = (wave >> 1) * 64;
  floatx4 acc[4][4] = {};

  int rA = lane >> 2;
  int gch = (lane & 3) ^ ((lane >> 3) & 3);
  int r0 = wave * 32 + rA;
  int r1 = r0 + 16;
  int gm0 = m0 + r0; gm0 = (gm0 < M) ? gm0 : (M - 1);
  int gm1 = m0 + r1; gm1 = (gm1 < M) ? gm1 : (M - 1);
  const float* pa0 = A + (size_t)gm0 * K + gch * 8;
  const float* pa1 = A + (size_t)gm1 * K + gch * 8;
  const __bf16* pb0 = Bblk + (size_t)r0 * K + gch * 8;
  const __bf16* pb1 = Bblk + (size_t)r1 * K + gch * 8;
  int lofsA = wave * 1024 + lane * 8;   // this thread's 16B LDS write slot
  int lofsB = wave * 1024;              // glds dest: wave-uniform base

  int fm = lane & 15, fg = lane >> 4;
  int sloto = (fg ^ ((fm >> 1) & 3)) * 8;

  // ---- prologue: stage k=0 into buffer 0 ----
  {
    floatx4 x0a = *(const floatx4*)(pa0);
    floatx4 x0b = *(const floatx4*)(pa0 + 4);
    floatx4 x1a = *(const floatx4*)(pa1);
    floatx4 x1b = *(const floatx4*)(pa1 + 4);
    glds16(pb0, sB + lofsB);
    glds16(pb1, sB + lofsB + 512);
    union { bf16x8 v; int4v i; } u0, u1;
#pragma unroll
    for (int q = 0; q < 4; q++) {
      u0.v[q] = (__bf16)x0a[q]; u0.v[q + 4] = (__bf16)x0b[q];
      u1.v[q] = (__bf16)x1a[q]; u1.v[q + 4] = (__bf16)x1b[q];
    }
    *(int4v*)(sA + lofsA) = u0.i;
    *(int4v*)(sA + lofsA + 512) = u1.i;
  }
  __syncthreads();

  // ---- main loop: compute buf(t&1), prefetch k(t+1) into buf(~t&1) ----
  for (int t = 0; t < 15; t++) {
    int cb = (t & 1) * 4096;
    int nb = cb ^ 4096;
    int k1 = t * 32 + 32;
    // issue next-step loads (async; latency hides under MFMA phase)
    floatx4 n0a = *(const floatx4*)(pa0 + k1);
    floatx4 n0b = *(const floatx4*)(pa0 + k1 + 4);
    floatx4 n1a = *(const floatx4*)(pa1 + k1);
    floatx4 n1b = *(const floatx4*)(pa1 + k1 + 4);
    glds16(pb0 + k1, sB + nb + lofsB);
    glds16(pb1 + k1, sB + nb + lofsB + 512);

    // compute current buffer
    bf16x8 af[4], bfr[4];
#pragma unroll
    for (int mt = 0; mt < 4; mt++)
      af[mt] = *(const bf16x8*)(sA + cb + (wm + mt * 16 + fm) * 32 + sloto);
#pragma unroll
    for (int nt = 0; nt < 4; nt++)
      bfr[nt] = *(const bf16x8*)(sB + cb + (wn + nt * 16 + fm) * 32 + sloto);
#pragma unroll
    for (int mt = 0; mt < 4; mt++)
#pragma unroll
      for (int nt = 0; nt < 4; nt++)
        acc[mt][nt] = __builtin_amdgcn_mfma_f32_16x16x32_bf16(af[mt], bfr[nt], acc[mt][nt], 0, 0, 0);

    // write next A tile (after MFMA so loads had time to land)
    union { bf16x8 v; int4v i; } u0, u1;
#pragma unroll
    for (int q = 0; q < 4; q++) {
      u0.v[q] = (__bf16)n0a[q]; u0.v[q + 4] = (__bf16)n0b[q];
      u1.v[q] = (__bf16)n1a[q]; u1.v[q + 4] = (__bf16)n1b[q];
    }
    *(int4v*)(sA + nb + lofsA) = u0.i;
    *(int4v*)(sA + nb + lofsA + 512) = u1.i;
    __syncthreads();  // drains glds (vmcnt) + ds_writes for buf nb
  }
  // ---- final k-step (t = 15, buffer 1) ----
  {
    int cb = 4096;
    bf16x8 af[4], bfr[4];
#pragma unroll
    for (int mt = 0; mt < 4; mt++)
      af[mt] = *(const bf16x8*)(sA + cb + (wm + mt * 16 + fm) * 32 + sloto);
#pragma unroll
    for (int nt = 0; nt < 4; nt++)
      bfr[nt] = *(const bf16x8*)(sB + cb + (wn + nt * 16 + fm) * 32 + sloto);
#pragma unroll
    for (int mt = 0; mt < 4; mt++)
#pragma unroll
      for (int nt = 0; nt < 4; nt++)
        acc[mt][nt] = __builtin_amdgcn_mfma_f32_16x16x32_bf16(af[mt], bfr[nt], acc[mt][nt], 0, 0, 0);
  }

  int colb = lane & 15, rbase = (lane >> 4) << 2;
#pragma unroll
  for (int mt = 0; mt < 4; mt++)
#pragma unroll
    for (int r = 0; r < 4; r++) {
      int gm = m0 + wm + mt * 16 + rbase + r;
      if (gm >= M) continue;
#pragma unroll
      for (int nt = 0; nt < 4; nt++) {
        int gc = blk * 128 + wn + nt * 16 + colb;
        float vv = acc[mt][nt][r] + bias[gc];
        vv = fmaxf(vv, 0.f);
        hb[(size_t)gm * 384 + gc] = (__bf16)vv;
      }
    }
}

// -------- S-GEMM: planar S_p[N,16] p=0..3 + R4[N,16] (p=4) ------------------
// Swapped-operand MFMA + 2 row-groups sharing B-frags (R6/R7-proven mapping).
// NEW: planar S output -- each hop later reads a dense [N,16] plane (full
// cache-line utilization) instead of a 16B slice of a 256B row.
__global__ __launch_bounds__(256) void k_sgemm(
    const __bf16* __restrict__ hb,   // [N,384]
    const __bf16* __restrict__ Ut,   // [80,384]
    float* __restrict__ S,           // 4 planes of [N,16] (p = 0..3)
    float* __restrict__ R4) {        // [N,16]  (p = 4)
  const int M = N_NODES;
  int wave = threadIdx.x >> 6, lane = threadIdx.x & 63;
  int fm = lane & 15, fg = lane >> 4;
  int m0 = blockIdx.x * 128 + wave * 32;
  floatx4 acc[2][5] = {};
  int r0 = m0 + fm;      r0 = (r0 < M) ? r0 : (M - 1);
  int r1 = m0 + 16 + fm; r1 = (r1 < M) ? r1 : (M - 1);
  const __bf16* pa0 = hb + (size_t)r0 * 384 + fg * 8;
  const __bf16* pa1 = hb + (size_t)r1 * 384 + fg * 8;
  const __bf16* pb  = Ut + (size_t)fm * 384 + fg * 8;
#pragma unroll 2
  for (int k0 = 0; k0 < 384; k0 += 32) {
    bf16x8 a0 = *(const bf16x8*)(pa0 + k0);
    bf16x8 a1 = *(const bf16x8*)(pa1 + k0);
#pragma unroll
    for (int nt = 0; nt < 5; nt++) {
      bf16x8 bv = *(const bf16x8*)(pb + (size_t)nt * 16 * 384 + k0);
      acc[0][nt] = __builtin_amdgcn_mfma_f32_16x16x32_bf16(bv, a0, acc[0][nt], 0, 0, 0);
      acc[1][nt] = __builtin_amdgcn_mfma_f32_16x16x32_bf16(bv, a1, acc[1][nt], 0, 0, 0);
    }
  }
  int gm0 = m0 + fm;
  if (gm0 < M) {
#pragma unroll
    for (int nt = 0; nt < 4; nt++)
      *(floatx4*)(S + (size_t)nt * N_NODES * 16 + (size_t)gm0 * 16 + fg * 4) = acc[0][nt];
    *(floatx4*)(R4 + (size_t)gm0 * 16 + fg * 4) = acc[0][4];
  }
  int gm1 = m0 + 16 + fm;
  if (gm1 < M) {
#pragma unroll
    for (int nt = 0; nt < 4; nt++)
      *(floatx4*)(S + (size_t)nt * N_NODES * 16 + (size_t)gm1 * 16 + fg * 4) = acc[1][nt];
    *(floatx4*)(R4 + (size_t)gm1 * 16 + fg * 4) = acc[1][4];
  }
}

// ---- Horner hop: Rout = A@Rin + Sp; 4 lanes/row, float4/lane (R7-proven) ---
// Sp is a dense [N,16] plane. FINAL adds const + log_softmax.
template <bool FINAL>
__global__ __launch_bounds__(256) void k_hop(
    const int* __restrict__ rowptr, const int2* __restrict__ epack,
    const float* __restrict__ Rin,      // [N,16]
    const float* __restrict__ Sp,       // [N,16] plane
    float* __restrict__ Rout,           // [N,16] (or out)
    const float* __restrict__ cc) {
  int tid = threadIdx.x;
  int rg = tid >> 2, l = tid & 3;
  int row = blockIdx.x * 64 + rg;
  if (row >= N_NODES) return;
  int s = rowptr[row], e = rowptr[row + 1];
  floatx4 a = *(const floatx4*)(Sp + (size_t)row * 16 + l * 4);
  for (int i = s; i < e; i += 4) {
    int take = e - i; if (take > 4) take = 4;
    int2 ed = (l < take) ? epack[i + l] : make_int2(0, 0);
#pragma unroll
    for (int j = 0; j < 4; j++) {
      int c = __shfl(ed.x, j, 4);
      float v = __int_as_float(__shfl(ed.y, j, 4));
      floatx4 g = *(const floatx4*)(Rin + (size_t)c * 16 + l * 4);
      a += v * g;
    }
  }
  if (!FINAL) {
    *(floatx4*)(Rout + (size_t)row * 16 + l * 4) = a;
  } else {
    floatx4 ccv = *(const floatx4*)(cc + l * 4);
    a += ccv;
    float m = fmaxf(fmaxf(a[0], a[1]), fmaxf(a[2], a[3]));
    m = fmaxf(m, __shfl_xor(m, 1, 4));
    m = fmaxf(m, __shfl_xor(m, 2, 4));
    float sm = expf(a[0] - m) + expf(a[1] - m) + expf(a[2] - m) + expf(a[3] - m);
    sm += __shfl_xor(sm, 1, 4);
    sm += __shfl_xor(sm, 2, 4);
    float ls = logf(sm);
    floatx4 o;
#pragma unroll
    for (int q = 0; q < 4; q++) o[q] = (a[q] - m) - ls;
    *(floatx4*)(Rout + (size_t)row * 16 + l * 4) = o;
  }
}

// ---------------- launch ----------------
extern "C" void kernel_launch(void* const* d_in, const int* in_sizes, int n_in,
                              void* d_out, int out_size, void* d_ws, size_t ws_size,
                              hipStream_t stream) {
  const float* x   = (const float*)d_in[0];
  const int*   adj = (const int*)d_in[1];
  const float* av  = (const float*)d_in[2];
  const float* w1  = (const float*)d_in[3];
  const float* b1  = (const float*)d_in[4];
  const float* w2  = (const float*)d_in[5];
  const float* b2  = (const float*)d_in[6];
  const float* wf  = (const float*)d_in[7];
  const float* bf  = (const float*)d_in[8];
  float* out = (float*)d_out;

  char* ws = (char*)d_ws;
  size_t off = 0;
  auto alloc = [&](size_t bytes) -> void* {
    off = (off + 255) & ~(size_t)255;
    void* p = ws + off;
    off += bytes;
    return p;
  };

  float* S    = (float*)alloc((size_t)N_NODES * 64 * 4);   // 4 planes [N,16]
  float* R4   = (float*)alloc((size_t)N_NODES * 16 * 4);
  float* RA   = (float*)alloc((size_t)N_NODES * 16 * 4);
  float* RB   = (float*)alloc((size_t)N_NODES * 16 * 4);
  __bf16* hb  = (__bf16*)alloc((size_t)N_NODES * 384 * 2);
  __bf16* w1t = (__bf16*)alloc((size_t)3 * 128 * FIN * 2);
  __bf16* Ut  = (__bf16*)alloc((size_t)80 * 384 * 2);
  int* rowptr = (int*)alloc((size_t)(N_NODES + 1) * 4);
  int* cnt    = (int*)alloc((size_t)N_NODES * 4);
  int* bsum   = (int*)alloc((size_t)SCAN_NB * 4);
  int* rankv  = (int*)alloc((size_t)N_EDGES * 4);
  int2* epack = (int2*)alloc((size_t)N_EDGES * 8);
  float* cc   = (float*)alloc(64);

  float* S0 = S;
  float* S1 = S + (size_t)N_NODES * 16;
  float* S2 = S + (size_t)N_NODES * 32;
  float* S3 = S + (size_t)N_NODES * 48;

  // CSR build (atomic-free placement) + prep, rank+prep fused
  hipMemsetAsync(cnt, 0, (size_t)N_NODES * 4, stream);
  k_rank_prep<<<RP_NRANK + PREP_NT1 + PREP_NU + 1, 256, 0, stream>>>(
      adj, cnt, rankv, w1, w1t, w2, wf, Ut, b2, bf, cc);
  k_scan_block<<<SCAN_NB, 256, 0, stream>>>(cnt, bsum);
  k_scan_fill<<<SCAN_NB, 256, 0, stream>>>(cnt, bsum, rowptr);
  k_place<<<(N_EDGES + 255) / 256, 256, 0, stream>>>(adj, av, rankv, rowptr, epack);

  // GEMM1: hb = relu(x@w1 + b1)  [N,384] bf16
  gemm1<<<8 * G1_TPX * 3, 256, 0, stream>>>(x, w1t, b1, hb);

  // S-GEMM: planar S_p[N,16] (p=0..3) + R4[N,16] (p=4)
  k_sgemm<<<(N_NODES + 127) / 128, 256, 0, stream>>>(hb, Ut, S, R4);

  // Horner: R = S_p + A*R, p = 3,2,1,0 (last fused with +const and log_softmax)
  int hop_grid = (N_NODES + 63) / 64;
  k_hop<false><<<hop_grid, 256, 0, stream>>>(rowptr, epack, R4, S3, RB, cc);
  k_hop<false><<<hop_grid, 256, 0, stream>>>(rowptr, epack, RB, S2, RA, cc);
  k_hop<false><<<hop_grid, 256, 0, stream>>>(rowptr, epack, RA, S1, RB, cc);
  k_hop<true><<<hop_grid, 256, 0, stream>>>(rowptr, epack, RB, S0, out, cc);
}